// Round 1
// baseline (1506.150 us; speedup 1.0000x reference)
//
#include <hip/hip_runtime.h>

// MiniS4D: B=16, D=512, N=64 states, L=4096.
// ws layout (bytes):
//   [0)        p_ar  32768 f32   (A_bar real)
//   [131072)   p_ai  32768 f32   (A_bar imag)
//   [262144)   p_wr  32768 f32   (W = C*B_bar real)
//   [393216)   p_wi  32768 f32   (W imag)
//   [524288)   p_lr  32768 f32   (A_bar^L real)
//   [655360)   p_li  32768 f32   (A_bar^L imag)
//   [786432)   pooled 8192 f32   (16x512 partial sums, memset 0)
//   [819200)   wbf   524288 bf16 (W_out as bf16)  -> 1867776
//   [1867776)  yg    33554432 bf16 (gelu output, layout (b,l,c))

#define UOFF_POOLED 786432
#define UOFF_WBF    819200
#define UOFF_YG     1867776

typedef __attribute__((ext_vector_type(8))) short short8;
typedef __attribute__((ext_vector_type(4))) float f32x4;

__device__ __forceinline__ unsigned short f2bf(float f) {
  unsigned int u = __float_as_uint(f);
  u = (u + 0x7FFF + ((u >> 16) & 1)) >> 16;  // RNE
  return (unsigned short)u;
}

// sum over 8-lane groups (lanes 8k..8k+7) with DPP only (no LDS latency):
// row_half_mirror (0x141) pairs i<->7-i within 8; then quad xor2 (0x4E), xor1 (0xB1).
__device__ __forceinline__ float octet_sum(float v) {
  float t;
  t = __int_as_float(__builtin_amdgcn_mov_dpp(__float_as_int(v), 0x141, 0xF, 0xF, true));
  v += t;
  t = __int_as_float(__builtin_amdgcn_mov_dpp(__float_as_int(v), 0x4E, 0xF, 0xF, true));
  v += t;
  t = __int_as_float(__builtin_amdgcn_mov_dpp(__float_as_int(v), 0xB1, 0xF, 0xF, true));
  v += t;
  return v;
}

// ---- derived SSM params: A_bar, W=C*B_bar, A_bar^L --------------------------
__global__ void k_params(const float* __restrict__ log_dt,
                         const float* __restrict__ log_A_real,
                         const float* __restrict__ A_imag,
                         const float* __restrict__ B_re, const float* __restrict__ B_im,
                         const float* __restrict__ C_re, const float* __restrict__ C_im,
                         float* __restrict__ p_ar, float* __restrict__ p_ai,
                         float* __restrict__ p_wr, float* __restrict__ p_wi,
                         float* __restrict__ p_lr, float* __restrict__ p_li) {
  int i = blockIdx.x * blockDim.x + threadIdx.x;   // 0..32767, d = i>>6
  int d = i >> 6;
  float dt  = expf(log_dt[d]);
  float Are = -expf(log_A_real[i]);
  float Aim = A_imag[i];
  float dre = dt * Are, dim = dt * Aim;
  float em  = expf(dre);
  float abr = em * cosf(dim);
  float abi = em * sinf(dim);
  // B_bar = (A_bar - 1)/A * B
  float nr = abr - 1.0f, ni = abi;
  float inv = 1.0f / (Are * Are + Aim * Aim);
  float br = (nr * Are + ni * Aim) * inv;
  float bi = (ni * Are - nr * Aim) * inv;
  float Br = B_re[i], Bi = B_im[i];
  float b2r = br * Br - bi * Bi;
  float b2i = br * Bi + bi * Br;
  float Cr = C_re[i], Ci = C_im[i];
  p_ar[i] = abr; p_ai[i] = abi;
  p_wr[i] = Cr * b2r - Ci * b2i;
  p_wi[i] = Cr * b2i + Ci * b2r;
  // A_bar^L = exp(dtA * 4096): closed form (underflow to 0 is genuinely negligible)
  float eL = expf(dre * 4096.0f);
  float phL = dim * 4096.0f;
  p_lr[i] = eL * cosf(phL);
  p_li[i] = eL * sinf(phL);
}

// ---- W_out fp32 -> bf16 -----------------------------------------------------
__global__ void k_wcvt(const float* __restrict__ w, unsigned short* __restrict__ wb, int n) {
  int i = blockIdx.x * blockDim.x + threadIdx.x;
  if (i < n) wb[i] = f2bf(w[i]);
}

// ---- SSM scan (REVERSED-kernel conv, per lax correlation semantics) ---------
// out[i] = Re sum_n W_n X_n[i];  X[L-1] = sum_m A^m u[m] (backward Horner),
// X[i-1] = A*X[i] - A^L*u[i]  (backward, stable).
// Mapping: 8 lanes ("octet") per (b,d); each lane owns 8 complex states.
__global__ __launch_bounds__(256) void k_scan(
    const float* __restrict__ u, const float* __restrict__ Dvec,
    const float* __restrict__ p_ar, const float* __restrict__ p_ai,
    const float* __restrict__ p_wr, const float* __restrict__ p_wi,
    const float* __restrict__ p_lr, const float* __restrict__ p_li,
    unsigned short* __restrict__ yg) {
  int tid = threadIdx.x;
  int g = blockIdx.x * 32 + (tid >> 3);   // (b,d) pair id, 0..8191
  int b = g >> 9;
  int d = g & 511;
  int r = tid & 7;
  int pbase = d * 64 + r * 8;

  float ar[8], ai[8], wr[8], wi[8], alr[8], ali[8];
#pragma unroll
  for (int j = 0; j < 8; j += 4) {
    float4 t;
    t = *(const float4*)(p_ar + pbase + j); ar[j]=t.x; ar[j+1]=t.y; ar[j+2]=t.z; ar[j+3]=t.w;
    t = *(const float4*)(p_ai + pbase + j); ai[j]=t.x; ai[j+1]=t.y; ai[j+2]=t.z; ai[j+3]=t.w;
    t = *(const float4*)(p_wr + pbase + j); wr[j]=t.x; wr[j+1]=t.y; wr[j+2]=t.z; wr[j+3]=t.w;
    t = *(const float4*)(p_wi + pbase + j); wi[j]=t.x; wi[j+1]=t.y; wi[j+2]=t.z; wi[j+3]=t.w;
    t = *(const float4*)(p_lr + pbase + j); alr[j]=t.x; alr[j+1]=t.y; alr[j+2]=t.z; alr[j+3]=t.w;
    t = *(const float4*)(p_li + pbase + j); ali[j]=t.x; ali[j+1]=t.y; ali[j+2]=t.z; ali[j+3]=t.w;
  }
  float Dd = Dvec[d];
  const float4* up = (const float4*)(u + (size_t)(b * 512 + d) * 4096);
  unsigned short* outp = yg + (size_t)b * (4096 * 512) + d;

  // ---- pass 1: H = sum_m A^m u[m]  (iterate m = L-1 .. 0; H = A*H + u[m])
  float Xr[8], Xi[8];
#pragma unroll
  for (int j = 0; j < 8; ++j) { Xr[j] = 0.f; Xi[j] = 0.f; }
  float4 cur = up[1023];
  for (int gi = 1023; gi >= 0; --gi) {
    float4 nxt = up[gi > 0 ? gi - 1 : 0];
#pragma unroll
    for (int s = 3; s >= 0; --s) {
      float uv = (s == 0) ? cur.x : (s == 1) ? cur.y : (s == 2) ? cur.z : cur.w;
#pragma unroll
      for (int j = 0; j < 8; ++j) {
        float hr = fmaf(ar[j], Xr[j], uv);
        hr = fmaf(-ai[j], Xi[j], hr);
        float hi = ai[j] * Xr[j];
        hi = fmaf(ar[j], Xi[j], hi);
        Xr[j] = hr; Xi[j] = hi;
      }
    }
    cur = nxt;
  }

  // ---- pass 2: i = L-1 .. 0: emit out[i] from X[i], then X -> X[i-1]
  cur = up[1023];
  for (int gi = 1023; gi >= 0; --gi) {
    float4 nxt = up[gi > 0 ? gi - 1 : 0];
#pragma unroll
    for (int s = 3; s >= 0; --s) {
      float uv = (s == 0) ? cur.x : (s == 1) ? cur.y : (s == 2) ? cur.z : cur.w;
      float a0 = 0.f, a1 = 0.f, a2 = 0.f, a3 = 0.f;  // 4 acc chains for ILP
#pragma unroll
      for (int j = 0; j < 8; ++j) {
        if (j & 1) { a1 = fmaf(wr[j], Xr[j], a1); a3 = fmaf(-wi[j], Xi[j], a3); }
        else       { a0 = fmaf(wr[j], Xr[j], a0); a2 = fmaf(-wi[j], Xi[j], a2); }
        float t0 = -alr[j] * uv;
        float xr = fmaf(ar[j], Xr[j], t0);
        xr = fmaf(-ai[j], Xi[j], xr);
        float t1 = -ali[j] * uv;
        float xi = fmaf(ai[j], Xr[j], t1);
        xi = fmaf(ar[j], Xi[j], xi);
        Xr[j] = xr; Xi[j] = xi;
      }
      float acc = (a0 + a2) + (a1 + a3);
      acc = octet_sum(acc);
      float y = fmaf(Dd, uv, acc);
      float ygl = 0.5f * y * (1.0f + erff(y * 0.70710678118654752f));
      if (r == 0) outp[(size_t)(gi * 4 + s) * 512] = f2bf(ygl);
    }
    cur = nxt;
  }
}

// ---- 1x1 conv (512->1024) + bias + GLU + sum-over-L, fused ------------------
// a-rows [mp0,mp0+64), g-rows [512+mp0,...). Block tile: Mpair=64, N=64 l's.
// 4 waves in 2x2 (m-half x n-half); each wave: 2 a-mtiles + 2 g-mtiles x 2 ntiles.
__global__ __launch_bounds__(256) void k_gemm(
    const unsigned short* __restrict__ wbf, const unsigned short* __restrict__ yg,
    const float* __restrict__ b_out, float* __restrict__ pooled) {
  __shared__ unsigned short lwa[64][88];  // +24 pad: 176B row stride, 16B aligned, 2-way-max banks
  __shared__ unsigned short lwg[64][88];
  __shared__ unsigned short ly[64][88];
  int tid = threadIdx.x;
  int mp0 = blockIdx.x * 64;
  int n0 = blockIdx.y * 64;           // global n = b*4096 + l
  int b = n0 >> 12;
  int wv = tid >> 6, lane = tid & 63;
  int mhalf = wv >> 1, nhalf = wv & 1;
  int lrow = lane & 15, quad = lane >> 4;
  f32x4 accA[2][2], accG[2][2];
#pragma unroll
  for (int mt = 0; mt < 2; ++mt)
#pragma unroll
    for (int nt = 0; nt < 2; ++nt) {
      accA[mt][nt] = (f32x4){0.f, 0.f, 0.f, 0.f};
      accG[mt][nt] = (f32x4){0.f, 0.f, 0.f, 0.f};
    }
  int srow = tid >> 2;
  int scol = (tid & 3) * 16;
  for (int kc = 0; kc < 512; kc += 64) {
    const uint4* pa = (const uint4*)(wbf + (size_t)(mp0 + srow) * 512 + kc + scol);
    const uint4* pg = (const uint4*)(wbf + (size_t)(512 + mp0 + srow) * 512 + kc + scol);
    const uint4* py = (const uint4*)(yg + (size_t)(n0 + srow) * 512 + kc + scol);
    uint4 va0 = pa[0], va1 = pa[1];
    uint4 vg0 = pg[0], vg1 = pg[1];
    uint4 vy0 = py[0], vy1 = py[1];
    *(uint4*)&lwa[srow][scol] = va0; *(uint4*)&lwa[srow][scol + 8] = va1;
    *(uint4*)&lwg[srow][scol] = vg0; *(uint4*)&lwg[srow][scol + 8] = vg1;
    *(uint4*)&ly[srow][scol] = vy0;  *(uint4*)&ly[srow][scol + 8] = vy1;
    __syncthreads();
#pragma unroll
    for (int kb = 0; kb < 2; ++kb) {
      int ko = kb * 32 + quad * 8;
      short8 bf[2], af[2], gf[2];
#pragma unroll
      for (int nt = 0; nt < 2; ++nt)
        bf[nt] = *(const short8*)&ly[nhalf * 32 + nt * 16 + lrow][ko];
#pragma unroll
      for (int mt = 0; mt < 2; ++mt) {
        af[mt] = *(const short8*)&lwa[mhalf * 32 + mt * 16 + lrow][ko];
        gf[mt] = *(const short8*)&lwg[mhalf * 32 + mt * 16 + lrow][ko];
      }
#pragma unroll
      for (int mt = 0; mt < 2; ++mt)
#pragma unroll
        for (int nt = 0; nt < 2; ++nt) {
          accA[mt][nt] = __builtin_amdgcn_mfma_f32_16x16x32_bf16(af[mt], bf[nt], accA[mt][nt], 0, 0, 0);
          accG[mt][nt] = __builtin_amdgcn_mfma_f32_16x16x32_bf16(gf[mt], bf[nt], accG[mt][nt], 0, 0, 0);
        }
    }
    __syncthreads();
  }
  // epilogue: bias, GLU, sum over cols (l), atomic into pooled[b][o]
#pragma unroll
  for (int mt = 0; mt < 2; ++mt) {
#pragma unroll
    for (int reg = 0; reg < 4; ++reg) {
      int olocal = mhalf * 32 + mt * 16 + quad * 4 + reg;
      float ba = b_out[mp0 + olocal];
      float bg = b_out[512 + mp0 + olocal];
      float h = 0.f;
#pragma unroll
      for (int nt = 0; nt < 2; ++nt) {
        float a = accA[mt][nt][reg] + ba;
        float gv = accG[mt][nt][reg] + bg;
        h += a / (1.0f + __expf(-gv));
      }
#pragma unroll
      for (int off = 1; off < 16; off <<= 1) h += __shfl_xor(h, off, 16);
      if (lrow == 0) atomicAdd(&pooled[b * 512 + mp0 + olocal], h);
    }
  }
}

// ---- decoder ----------------------------------------------------------------
__global__ void k_final(const float* __restrict__ pooled, const float* __restrict__ W_dec,
                        const float* __restrict__ b_dec, float* __restrict__ out) {
  int b = blockIdx.x;
  int lane = threadIdx.x;
  float s = 0.f;
#pragma unroll
  for (int j = 0; j < 8; ++j) s += pooled[b * 512 + lane + 64 * j] * W_dec[lane + 64 * j];
#pragma unroll
  for (int off = 1; off < 64; off <<= 1) s += __shfl_xor(s, off, 64);
  if (lane == 0) out[b] = s * (1.0f / 4096.0f) + b_dec[0];
}

extern "C" void kernel_launch(void* const* d_in, const int* in_sizes, int n_in,
                              void* d_out, int out_size, void* d_ws, size_t ws_size,
                              hipStream_t stream) {
  const float* u          = (const float*)d_in[0];
  const float* log_dt     = (const float*)d_in[1];
  const float* log_A_real = (const float*)d_in[2];
  const float* A_imag     = (const float*)d_in[3];
  const float* B_re       = (const float*)d_in[4];
  const float* B_im       = (const float*)d_in[5];
  const float* C_re       = (const float*)d_in[6];
  const float* C_im       = (const float*)d_in[7];
  const float* Dv         = (const float*)d_in[8];
  const float* W_out      = (const float*)d_in[9];
  const float* b_out      = (const float*)d_in[10];
  const float* W_dec      = (const float*)d_in[11];
  const float* b_dec      = (const float*)d_in[12];

  float* ws = (float*)d_ws;
  float* p_ar = ws;
  float* p_ai = ws + 32768;
  float* p_wr = ws + 65536;
  float* p_wi = ws + 98304;
  float* p_lr = ws + 131072;
  float* p_li = ws + 163840;
  float* pooled = (float*)((char*)d_ws + UOFF_POOLED);
  unsigned short* wbf = (unsigned short*)((char*)d_ws + UOFF_WBF);
  unsigned short* yg = (unsigned short*)((char*)d_ws + UOFF_YG);

  hipMemsetAsync(pooled, 0, 16 * 512 * sizeof(float), stream);
  k_params<<<128, 256, 0, stream>>>(log_dt, log_A_real, A_imag, B_re, B_im, C_re, C_im,
                                    p_ar, p_ai, p_wr, p_wi, p_lr, p_li);
  k_wcvt<<<2048, 256, 0, stream>>>(W_out, wbf, 1024 * 512);
  k_scan<<<256, 256, 0, stream>>>(u, Dv, p_ar, p_ai, p_wr, p_wi, p_lr, p_li, yg);
  k_gemm<<<dim3(8, 1024), 256, 0, stream>>>(wbf, yg, b_out, pooled);
  k_final<<<16, 64, 0, stream>>>(pooled, W_dec, b_dec, (float*)d_out);
}